// Round 17
// baseline (198.683 us; speedup 1.0000x reference)
//
#include <hip/hip_runtime.h>
#include <hip/hip_fp16.h>

#define NNODES 50000
#define NEDGES 800000
#define NEG_SLOPE 0.2f
#define NTOT (NEDGES + NNODES)
#define NB_NODE ((NNODES + 255) / 256)   // 196 buckets of 256 nodes
#define CHUNK 4096
#define NCHUNK ((NEDGES + CHUNK - 1) / CHUNK)   // 196 chunks
#define CAPB 4800                         // per-bucket capacity: mean 4082 +11 sigma
#define CNTSTRIDE 16                      // 64 B padding: one counter per cache line
#define ZPAD (NTOT + 32)                  // zeroed alpha entry for masked edges

typedef _Float16 half8 __attribute__((ext_vector_type(8)));
typedef _Float16 half4 __attribute__((ext_vector_type(4)));
typedef float f32x4 __attribute__((ext_vector_type(4)));

// ---------------- fused setup + bucket scatter (independent block ranges) ----------------
__global__ void setup_scatter(const float* __restrict__ x, const float* __restrict__ W1,
                              const float* __restrict__ att_src, const float* __restrict__ att_dst,
                              const float* __restrict__ W2,
                              const int* __restrict__ srcs, const int* __restrict__ dsts,
                              int* __restrict__ bucket_cnt, int* __restrict__ bucketbuf,
                              float* __restrict__ x16, float* __restrict__ asrc4,
                              float* __restrict__ adst4, _Float16* __restrict__ W2T) {
    int t = threadIdx.x;
    __shared__ unsigned short meta[CHUNK];
    __shared__ int lcnt[NB_NODE], lbase[NB_NODE];
    __shared__ float swa[16][4], swd[16][4];
    if (blockIdx.x < NCHUNK) {
        int b = blockIdx.x;
        for (int i = t; i < NB_NODE; i += 256) lcnt[i] = 0;
        __syncthreads();
        int e0 = b * CHUNK;
        int e1 = e0 + CHUNK; if (e1 > NEDGES) e1 = NEDGES;
        for (int e = e0 + t; e < e1; e += 256) {
            int d = dsts[e];
            meta[e - e0] = (unsigned short)d;
            atomicAdd(&lcnt[d >> 8], 1);
        }
        __syncthreads();
        for (int i = t; i < NB_NODE; i += 256) {
            int c = lcnt[i];
            lbase[i] = c ? atomicAdd(&bucket_cnt[i * CNTSTRIDE], c) : 0;
        }
        __syncthreads();
        for (int i = t; i < NB_NODE; i += 256) lcnt[i] = 0;   // reuse as cursor
        __syncthreads();
        for (int e = e0 + t; e < e1; e += 256) {
            int dv = meta[e - e0];
            int bk = dv >> 8;
            int pos = lbase[bk] + atomicAdd(&lcnt[bk], 1);
            if (pos < CAPB) bucketbuf[bk * CAPB + pos] = ((dv & 255) << 16) | srcs[e];
        }
    } else {
        int b = blockIdx.x - NCHUNK;
        if (t < 128) {
            int k = (t & 63) >> 2, h = t & 3;
            float s = 0.f;
            if (k < 15) {
                const float* att = (t < 64) ? att_src : att_dst;
#pragma unroll 16
                for (int d = 0; d < 64; ++d)
                    s += W1[k * 256 + h * 64 + d] * att[h * 64 + d];
            }
            if (t < 64) swa[k][h] = s; else swd[k][h] = s;
        }
        int tid = b * 256 + t;
        if (tid < 64 * 256) {
            int n = tid >> 8, k = tid & 255;
            W2T[n * 256 + k] = (_Float16)W2[k * 64 + n];
        }
        __syncthreads();
        int nid = tid;
        if (nid < NNODES) {
            float xv[16];
#pragma unroll
            for (int k = 0; k < 15; ++k) xv[k] = x[nid * 15 + k];
            xv[15] = 0.f;
#pragma unroll
            for (int k = 0; k < 16; k += 4)
                *(float4*)(x16 + (size_t)nid * 16 + k) =
                    make_float4(xv[k], xv[k+1], xv[k+2], xv[k+3]);
            float ps[4] = {0.f, 0.f, 0.f, 0.f}, pd[4] = {0.f, 0.f, 0.f, 0.f};
#pragma unroll
            for (int k = 0; k < 15; ++k)
#pragma unroll
                for (int h = 0; h < 4; ++h) {
                    ps[h] += xv[k] * swa[k][h];
                    pd[h] += xv[k] * swd[k][h];
                }
            *(float4*)(asrc4 + nid * 4) = make_float4(ps[0], ps[1], ps[2], ps[3]);
            *(float4*)(adst4 + nid * 4) = make_float4(pd[0], pd[1], pd[2], pd[3]);
        }
    }
}

// ------- sort_kernel: hist + scan + ONE alloc atomic + LDS sort + NORMALIZED alpha ----
// Thread t owns dst-local t. After sorting, computes per-dst z (4 heads) over its
// contiguous segment, then the emit loop writes alpha = w/z. layer1 then needs no
// z accumulation or division at all (sum(alpha) == 1 by construction).
__global__ void sort_kernel(const int* __restrict__ bucket_cnt, const int* __restrict__ bucketbuf,
                            const float4* __restrict__ asrc4, const float4* __restrict__ adst4,
                            int* __restrict__ alloc, int2* __restrict__ row_desc,
                            int* __restrict__ srclist, float4* __restrict__ sw4) {
    int b = blockIdx.x, t = threadIdx.x, lane = t & 63, wid = t >> 6;
    __shared__ int hist[256], cur[256], ws[4];
    __shared__ int raw[CAPB];       // bucket entries, read once from global
    __shared__ int sorted[5120];    // n + 256 self-loops <= 5056
    __shared__ float4 sadst[256];
    __shared__ float4 zinv[256];
    __shared__ int sbase;
    int nid = b * 256 + t;
    hist[t] = (nid < NNODES) ? 1 : 0;          // self-loop counted here
    if (nid < NNODES) sadst[t] = adst4[nid];
    if (b == 0 && t == 0) sw4[ZPAD] = make_float4(0.f, 0.f, 0.f, 0.f);
    __syncthreads();
    int n = bucket_cnt[b * CNTSTRIDE]; if (n > CAPB) n = CAPB;
    for (int i = t; i < n; i += 256) {
        int e = bucketbuf[(size_t)b * CAPB + i];
        raw[i] = e;
        atomicAdd(&hist[e >> 16], 1);
    }
    __syncthreads();
    int v = hist[t];
    int incl = v;
#pragma unroll
    for (int off = 1; off < 64; off <<= 1) {
        int u = __shfl_up(incl, off, 64);
        if (lane >= off) incl += u;
    }
    if (lane == 63) ws[wid] = incl;
    __syncthreads();
    int w0 = ws[0], w1 = ws[1], w2 = ws[2], w3 = ws[3];
    int woff = (wid > 0 ? w0 : 0) + (wid > 1 ? w1 : 0) + (wid > 2 ? w2 : 0);
    int excl = woff + (incl - v);
    int totalb = w0 + w1 + w2 + w3;
    if (t == 0) sbase = atomicAdd(alloc, totalb);    // ONE global atomic per bucket
    __syncthreads();
    int base = sbase;
    cur[t] = excl;
    if (nid < NNODES) row_desc[nid] = make_int2(base + excl, v);
    __syncthreads();
    if (nid < NNODES) {                              // self-loop inserted directly
        int pos = atomicAdd(&cur[t], 1);
        sorted[pos] = (t << 16) | nid;
    }
    for (int i = t; i < n; i += 256) {
        int e = raw[i];
        int pos = atomicAdd(&cur[e >> 16], 1);
        sorted[pos] = e;
    }
    __syncthreads();
    // per-dst softmax denominator over the contiguous segment [excl, excl+v)
    if (nid < NNODES) {
        float4 ad = sadst[t];
        float z0 = 0.f, z1 = 0.f, z2 = 0.f, z3 = 0.f;
        for (int i = 0; i < v; ++i) {
            int s = sorted[excl + i] & 0xFFFF;
            float4 as = asrc4[s];
            float e0 = as.x + ad.x, e1 = as.y + ad.y, e2 = as.z + ad.z, e3 = as.w + ad.w;
            e0 = fmaxf(e0, NEG_SLOPE * e0); e1 = fmaxf(e1, NEG_SLOPE * e1);
            e2 = fmaxf(e2, NEG_SLOPE * e2); e3 = fmaxf(e3, NEG_SLOPE * e3);
            z0 += __expf(e0); z1 += __expf(e1); z2 += __expf(e2); z3 += __expf(e3);
        }
        zinv[t] = make_float4(1.f / z0, 1.f / z1, 1.f / z2, 1.f / z3);
    }
    __syncthreads();
    for (int i = t; i < totalb; i += 256) {
        int e = sorted[i];
        int s = e & 0xFFFF, dl = e >> 16;
        srclist[base + i] = s;
        float4 as = asrc4[s];
        float4 ad = sadst[dl];
        float4 zi = zinv[dl];
        float e0 = as.x + ad.x, e1 = as.y + ad.y, e2 = as.z + ad.z, e3 = as.w + ad.w;
        e0 = fmaxf(e0, NEG_SLOPE * e0); e1 = fmaxf(e1, NEG_SLOPE * e1);
        e2 = fmaxf(e2, NEG_SLOPE * e2); e3 = fmaxf(e3, NEG_SLOPE * e3);
        sw4[base + i] = make_float4(__expf(e0) * zi.x, __expf(e1) * zi.y,
                                    __expf(e2) * zi.z, __expf(e3) * zi.w);
    }
}

// -------- layer 1 FUSED: aggregate (4 nodes/wave, pre-normalized alpha) + W1 + ELU
// -------- + W2 MFMA GEMM. No z accumulation, no divisions (sum alpha == 1).
__global__ __launch_bounds__(256) void layer1_fused(
        const float* __restrict__ x16, const int2* __restrict__ row_desc,
        const int* __restrict__ srclist, const float4* __restrict__ sw4,
        const float* __restrict__ W1, const float* __restrict__ b1,
        const _Float16* __restrict__ W2T,
        const float* __restrict__ att_src2, const float* __restrict__ att_dst2,
        __half* __restrict__ h2, float* __restrict__ as2, float* __restrict__ ad2) {
    int wid = threadIdx.x >> 6, lane = threadIdx.x & 63;
    int g = lane >> 4, k = lane & 15;
    int base = blockIdx.x * 16 + wid * 4;      // 4 nodes for this wave, 16 per block
    int nid = base + g;
    int2 rd = row_desc[nid];
    int beg = rd.x, cnt = rd.y;
    int cmax = cnt;
    cmax = max(cmax, __shfl_xor(cmax, 16, 64));
    cmax = max(cmax, __shfl_xor(cmax, 32, 64));
    cmax = __builtin_amdgcn_readfirstlane(cmax);
    int gb = g * 16;
    float4 acc = {0.f, 0.f, 0.f, 0.f};
    for (int c0 = 0; c0 < cmax; c0 += 16) {
        int sv = (c0 + k < cnt) ? srclist[beg + c0 + k] : 0;   // group's edge buffer
        int bmax = cmax - c0; if (bmax > 16) bmax = 16;
        for (int j = 0; j < bmax; j += 4) {
            int i0 = c0 + j;
            int s0 = __shfl(sv, gb + j + 0, 64);
            int s1 = __shfl(sv, gb + j + 1, 64);
            int s2 = __shfl(sv, gb + j + 2, 64);
            int s3 = __shfl(sv, gb + j + 3, 64);
            int w0i = (i0 + 0 < cnt) ? beg + i0 + 0 : ZPAD;    // index-redirect mask
            int w1i = (i0 + 1 < cnt) ? beg + i0 + 1 : ZPAD;
            int w2i = (i0 + 2 < cnt) ? beg + i0 + 2 : ZPAD;
            int w3i = (i0 + 3 < cnt) ? beg + i0 + 3 : ZPAD;
            float4 w0 = sw4[w0i];
            float4 w1 = sw4[w1i];
            float4 w2 = sw4[w2i];
            float4 w3 = sw4[w3i];
            float x0 = x16[s0 * 16 + k];
            float x1 = x16[s1 * 16 + k];
            float x2 = x16[s2 * 16 + k];
            float x3 = x16[s3 * 16 + k];
            acc.x = fmaf(w3.x, x3, fmaf(w2.x, x2, fmaf(w1.x, x1, fmaf(w0.x, x0, acc.x))));
            acc.y = fmaf(w3.y, x3, fmaf(w2.y, x2, fmaf(w1.y, x1, fmaf(w0.y, x0, acc.y))));
            acc.z = fmaf(w3.z, x3, fmaf(w2.z, x2, fmaf(w1.z, x1, fmaf(w0.z, x0, acc.z))));
            acc.w = fmaf(w3.w, x3, fmaf(w2.w, x2, fmaf(w1.w, x1, fmaf(w0.w, x0, acc.w))));
        }
    }
    __shared__ float sacc[4][4][64];           // [wave][node][h*16+k]
    sacc[wid][g][0 * 16 + k] = acc.x;
    sacc[wid][g][1 * 16 + k] = acc.y;
    sacc[wid][g][2 * 16 + k] = acc.z;
    sacc[wid][g][3 * 16 + k] = acc.w;
    // wave-coherent LDS: no barrier. Project 4 nodes with W1 loaded once per kk.
    int c = lane, h2i = c >> 4;
    float4 bo = *(const float4*)(b1 + c * 4);
    float4 o0 = bo, o1 = bo, o2 = bo, o3 = bo;
#pragma unroll
    for (int kk = 0; kk < 15; ++kk) {
        float4 wv = *(const float4*)(W1 + kk * 256 + c * 4);   // L1-resident (15 KB)
        float a0 = sacc[wid][0][h2i * 16 + kk];
        float a1 = sacc[wid][1][h2i * 16 + kk];
        float a2 = sacc[wid][2][h2i * 16 + kk];
        float a3 = sacc[wid][3][h2i * 16 + kk];
        o0.x = fmaf(a0, wv.x, o0.x); o0.y = fmaf(a0, wv.y, o0.y);
        o0.z = fmaf(a0, wv.z, o0.z); o0.w = fmaf(a0, wv.w, o0.w);
        o1.x = fmaf(a1, wv.x, o1.x); o1.y = fmaf(a1, wv.y, o1.y);
        o1.z = fmaf(a1, wv.z, o1.z); o1.w = fmaf(a1, wv.w, o1.w);
        o2.x = fmaf(a2, wv.x, o2.x); o2.y = fmaf(a2, wv.y, o2.y);
        o2.z = fmaf(a2, wv.z, o2.z); o2.w = fmaf(a2, wv.w, o2.w);
        o3.x = fmaf(a3, wv.x, o3.x); o3.y = fmaf(a3, wv.y, o3.y);
        o3.z = fmaf(a3, wv.z, o3.z); o3.w = fmaf(a3, wv.w, o3.w);
    }
    __shared__ _Float16 ot[16][264];           // block's out1 tile (pad 8: 16B-align rows)
    float4 ov[4] = {o0, o1, o2, o3};
#pragma unroll
    for (int gp = 0; gp < 4; ++gp) {
        float p0 = ov[gp].x, p1 = ov[gp].y, p2 = ov[gp].z, p3 = ov[gp].w;
        p0 = p0 > 0.f ? p0 : __expf(p0) - 1.f;   // ELU
        p1 = p1 > 0.f ? p1 : __expf(p1) - 1.f;
        p2 = p2 > 0.f ? p2 : __expf(p2) - 1.f;
        p3 = p3 > 0.f ? p3 : __expf(p3) - 1.f;
        half4 st;
        st[0] = (_Float16)p0; st[1] = (_Float16)p1;
        st[2] = (_Float16)p2; st[3] = (_Float16)p3;
        *(half4*)&ot[wid * 4 + gp][c * 4] = st;
    }
    __syncthreads();
    // ---- phase 2: GEMM 16x256 @ 256x64, wave wid owns N-tile [wid*16, wid*16+16) ----
    int m16 = lane & 15, quad = lane >> 4;
    f32x4 cc = {0.f, 0.f, 0.f, 0.f};
#pragma unroll
    for (int k0 = 0; k0 < 256; k0 += 32) {
        half8 a = *(const half8*)&ot[m16][k0 + quad * 8];
        half8 bf = *(const half8*)(W2T + (size_t)(wid * 16 + m16) * 256 + k0 + quad * 8);
        cc = __builtin_amdgcn_mfma_f32_16x16x32_f16(a, bf, cc, 0, 0, 0);
    }
    __shared__ _Float16 h2t[16][72];
#pragma unroll
    for (int r = 0; r < 4; ++r)
        h2t[quad * 4 + r][wid * 16 + m16] = (_Float16)cc[r];
    __syncthreads();
    int trow = threadIdx.x >> 4, tc = threadIdx.x & 15;   // 16 rows x 16 dim-quads
    int rg = blockIdx.x * 16 + trow;
    half4 hval = *(const half4*)&h2t[trow][tc * 4];
    *(half4*)((_Float16*)h2 + (size_t)rg * 64 + tc * 4) = hval;
    float ps = 0.f, pd = 0.f;
#pragma unroll
    for (int j = 0; j < 4; ++j) {
        float v = (float)hval[j];
        ps += v * att_src2[tc * 4 + j];
        pd += v * att_dst2[tc * 4 + j];
    }
    ps += __shfl_xor(ps, 1, 64); ps += __shfl_xor(ps, 2, 64);
    ps += __shfl_xor(ps, 4, 64); ps += __shfl_xor(ps, 8, 64);
    pd += __shfl_xor(pd, 1, 64); pd += __shfl_xor(pd, 2, 64);
    pd += __shfl_xor(pd, 4, 64); pd += __shfl_xor(pd, 8, 64);
    if (tc == 0) { as2[rg] = ps; ad2[rg] = pd; }
}

// 2 nodes/wave; weights computed vectorized ONCE per 32-edge chunk (masked at source),
// inner loop = 2 shfl + gather + hfma2. Output into out_partial via LDS + atomics.
__global__ void layer2_aggr(const __half* __restrict__ h2, const int2* __restrict__ row_desc,
                            const int* __restrict__ srclist,
                            const float* __restrict__ as2, const float* __restrict__ ad2,
                            const float* __restrict__ b2, float* __restrict__ out_partial) {
    int wid = threadIdx.x >> 6, lane = threadIdx.x & 63;
    int sub = lane >> 5, l2 = lane & 31;
    int nid = blockIdx.x * 8 + wid * 2 + sub;
    __shared__ float baccum[64];
    if (threadIdx.x < 64) baccum[threadIdx.x] = 0.f;
    int2 rd = row_desc[nid];
    int beg = rd.x, cnt = rd.y;
    int cmax = max(cnt, __shfl_xor(cnt, 32, 64));
    cmax = __builtin_amdgcn_readfirstlane(cmax);
    float ad = ad2[nid];
    const __half2* hp = (const __half2*)h2;
    __half2 acc2 = __float2half2_rn(0.f);
    float zs = 0.f;
    int sb = sub * 32;
    __syncthreads();
    for (int c0 = 0; c0 < cmax; c0 += 32) {
        bool lv = (c0 + l2) < cnt;
        int sv = lv ? srclist[beg + c0 + l2] : 0;
        float el = as2[sv] + ad;                 // chunk-vectorized weight compute
        el = fmaxf(el, NEG_SLOPE * el);
        float wl = lv ? __expf(el) : 0.f;        // masked at source: inner needs no check
        int bmax = cmax - c0; if (bmax > 32) bmax = 32;
        for (int j = 0; j < bmax; j += 4) {
#pragma unroll
            for (int u = 0; u < 4; ++u) {
                int jj = j + u;
                int s = __shfl(sv, sb + jj, 64);
                float wv = __shfl(wl, sb + jj, 64);
                __half2 gv = hp[s * 32 + l2];
                zs += wv;
                acc2 = __hfma2(__float2half2_rn(wv), gv, acc2);
            }
        }
    }
    float2 f = __half22float2(acc2);
    float rz = 1.f / zs;
    float2 bo = *(const float2*)(b2 + l2 * 2);
    atomicAdd(&baccum[l2 * 2 + 0], f.x * rz + bo.x);   // LDS: 8 contributions/element
    atomicAdd(&baccum[l2 * 2 + 1], f.y * rz + bo.y);
    __syncthreads();
    if (threadIdx.x < 64)
        atomicAdd(&out_partial[(blockIdx.x & 255) * 64 + threadIdx.x], baccum[threadIdx.x]);
}

// single block: reduce out_partial[256][64] -> dout (direct write, no memset needed)
__global__ void reduce_kernel(const float* __restrict__ out_partial, float* __restrict__ dout) {
    int t = threadIdx.x;
    int col = t & 63, row = t >> 6;
    float acc = 0.f;
    for (int s = row; s < 256; s += 4)
        acc += out_partial[s * 64 + col];
    __shared__ float sh[256];
    sh[t] = acc;
    __syncthreads();
    if (t < 64)
        dout[t] = (sh[t] + sh[t + 64] + sh[t + 128] + sh[t + 192]) * (1.0f / NNODES);
}

// ---------------- launch ----------------

extern "C" void kernel_launch(void* const* d_in, const int* in_sizes, int n_in,
                              void* d_out, int out_size, void* d_ws, size_t ws_size,
                              hipStream_t stream) {
    const float* x        = (const float*)d_in[0];
    const int*   ei       = (const int*)d_in[1];   // [2, E] -> src row then dst row
    const float* W1       = (const float*)d_in[2];
    const float* att_src1 = (const float*)d_in[3];
    const float* att_dst1 = (const float*)d_in[4];
    const float* b1       = (const float*)d_in[5];
    const float* W2       = (const float*)d_in[6];
    const float* att_src2 = (const float*)d_in[7];
    const float* att_dst2 = (const float*)d_in[8];
    const float* b2       = (const float*)d_in[9];
    float* out = (float*)d_out;

    char* ws = (char*)d_ws;
    size_t off = 0;
    auto take = [&](size_t bytes) -> char* {
        char* p = ws + off;
        off = (off + bytes + 255) & ~(size_t)255;
        return p;
    };
    // --- zeroed region: bucket_cnt | alloc | out_partial (contiguous, one memset) ---
    int*      bucket_cnt  = (int*)take((size_t)NB_NODE * CNTSTRIDE * sizeof(int));  // 12544 B
    int*      alloc       = (int*)take(256);                                        // 256 B
    float*    out_partial = (float*)take(256 * 64 * sizeof(float));                 // 65536 B
    size_t    zero_bytes  = (size_t)NB_NODE * CNTSTRIDE * sizeof(int) + 256
                            + 256 * 64 * sizeof(float);
    // --- rest ---
    int*      bucketbuf  = (int*)take((size_t)NB_NODE * CAPB * sizeof(int));
    int2*     row_desc   = (int2*)take((size_t)NNODES * sizeof(int2));
    int*      srclist    = (int*)take(((size_t)NTOT + 64) * sizeof(int));
    float*    sw4        = (float*)take(((size_t)NTOT + 64) * 4 * sizeof(float));
    float*    x16        = (float*)take((size_t)NNODES * 16 * sizeof(float));
    float*    asrc4      = (float*)take((size_t)NNODES * 4 * sizeof(float));
    float*    adst4      = (float*)take((size_t)NNODES * 4 * sizeof(float));
    _Float16* W2T        = (_Float16*)take(64 * 256 * sizeof(_Float16));
    __half*   h2         = (__half*)take((size_t)NNODES * 64 * sizeof(__half));
    float*    as2        = (float*)take((size_t)NNODES * sizeof(float));
    float*    ad2        = (float*)take((size_t)NNODES * sizeof(float));

    const int* srcs = ei;
    const int* dsts = ei + NEDGES;

    hipMemsetAsync(bucket_cnt, 0, zero_bytes, stream);

    setup_scatter<<<NCHUNK + NB_NODE, 256, 0, stream>>>(x, W1, att_src1, att_dst1, W2,
                                                        srcs, dsts, bucket_cnt, bucketbuf,
                                                        x16, asrc4, adst4, W2T);
    sort_kernel<<<NB_NODE, 256, 0, stream>>>(bucket_cnt, bucketbuf,
                                             (const float4*)asrc4, (const float4*)adst4,
                                             alloc, row_desc, srclist, (float4*)sw4);

    layer1_fused<<<NNODES / 16, 256, 0, stream>>>(x16, row_desc, srclist, (const float4*)sw4,
                                                  W1, b1, W2T, att_src2, att_dst2,
                                                  h2, as2, ad2);

    layer2_aggr<<<NNODES / 8, 256, 0, stream>>>(h2, row_desc, srclist, as2, ad2, b2,
                                                out_partial);

    reduce_kernel<<<1, 256, 0, stream>>>(out_partial, out);
}

// Round 18
// 191.978 us; speedup vs baseline: 1.0349x; 1.0349x over previous
//
#include <hip/hip_runtime.h>
#include <hip/hip_fp16.h>

#define NNODES 50000
#define NEDGES 800000
#define NEG_SLOPE 0.2f
#define NTOT (NEDGES + NNODES)
#define NB_NODE ((NNODES + 255) / 256)   // 196 buckets of 256 nodes
#define CHUNK 4096
#define NCHUNK ((NEDGES + CHUNK - 1) / CHUNK)   // 196 chunks
#define CAPB 4800                         // per-bucket capacity: mean 4082 +11 sigma
#define CNTSTRIDE 16                      // 64 B padding: one counter per cache line
#define ZPAD (NTOT + 32)                  // zeroed sw4 entry for masked edges

typedef _Float16 half8 __attribute__((ext_vector_type(8)));
typedef _Float16 half4 __attribute__((ext_vector_type(4)));
typedef float f32x4 __attribute__((ext_vector_type(4)));

// ---------------- fused setup + bucket scatter (independent block ranges) ----------------
__global__ void setup_scatter(const float* __restrict__ x, const float* __restrict__ W1,
                              const float* __restrict__ att_src, const float* __restrict__ att_dst,
                              const float* __restrict__ W2,
                              const int* __restrict__ srcs, const int* __restrict__ dsts,
                              int* __restrict__ bucket_cnt, int* __restrict__ bucketbuf,
                              float* __restrict__ x16, float* __restrict__ asrc4,
                              float* __restrict__ adst4, _Float16* __restrict__ W2T) {
    int t = threadIdx.x;
    __shared__ unsigned short meta[CHUNK];
    __shared__ int lcnt[NB_NODE], lbase[NB_NODE];
    __shared__ float swa[16][4], swd[16][4];
    if (blockIdx.x < NCHUNK) {
        int b = blockIdx.x;
        for (int i = t; i < NB_NODE; i += 256) lcnt[i] = 0;
        __syncthreads();
        int e0 = b * CHUNK;
        int e1 = e0 + CHUNK; if (e1 > NEDGES) e1 = NEDGES;
        for (int e = e0 + t; e < e1; e += 256) {
            int d = dsts[e];
            meta[e - e0] = (unsigned short)d;
            atomicAdd(&lcnt[d >> 8], 1);
        }
        __syncthreads();
        for (int i = t; i < NB_NODE; i += 256) {
            int c = lcnt[i];
            lbase[i] = c ? atomicAdd(&bucket_cnt[i * CNTSTRIDE], c) : 0;
        }
        __syncthreads();
        for (int i = t; i < NB_NODE; i += 256) lcnt[i] = 0;   // reuse as cursor
        __syncthreads();
        for (int e = e0 + t; e < e1; e += 256) {
            int dv = meta[e - e0];
            int bk = dv >> 8;
            int pos = lbase[bk] + atomicAdd(&lcnt[bk], 1);
            if (pos < CAPB) bucketbuf[bk * CAPB + pos] = ((dv & 255) << 16) | srcs[e];
        }
    } else {
        int b = blockIdx.x - NCHUNK;
        if (t < 128) {
            int k = (t & 63) >> 2, h = t & 3;
            float s = 0.f;
            if (k < 15) {
                const float* att = (t < 64) ? att_src : att_dst;
#pragma unroll 16
                for (int d = 0; d < 64; ++d)
                    s += W1[k * 256 + h * 64 + d] * att[h * 64 + d];
            }
            if (t < 64) swa[k][h] = s; else swd[k][h] = s;
        }
        int tid = b * 256 + t;
        if (tid < 64 * 256) {
            int n = tid >> 8, k = tid & 255;
            W2T[n * 256 + k] = (_Float16)W2[k * 64 + n];
        }
        __syncthreads();
        int nid = tid;
        if (nid < NNODES) {
            float xv[16];
#pragma unroll
            for (int k = 0; k < 15; ++k) xv[k] = x[nid * 15 + k];
            xv[15] = 0.f;
#pragma unroll
            for (int k = 0; k < 16; k += 4)
                *(float4*)(x16 + (size_t)nid * 16 + k) =
                    make_float4(xv[k], xv[k+1], xv[k+2], xv[k+3]);
            float ps[4] = {0.f, 0.f, 0.f, 0.f}, pd[4] = {0.f, 0.f, 0.f, 0.f};
#pragma unroll
            for (int k = 0; k < 15; ++k)
#pragma unroll
                for (int h = 0; h < 4; ++h) {
                    ps[h] += xv[k] * swa[k][h];
                    pd[h] += xv[k] * swd[k][h];
                }
            *(float4*)(asrc4 + nid * 4) = make_float4(ps[0], ps[1], ps[2], ps[3]);
            *(float4*)(adst4 + nid * 4) = make_float4(pd[0], pd[1], pd[2], pd[3]);
        }
    }
}

// ------- sort_kernel: hist + scan + ONE global alloc atomic + LDS counting sort -------
__global__ void sort_kernel(const int* __restrict__ bucket_cnt, const int* __restrict__ bucketbuf,
                            const float4* __restrict__ asrc4, const float4* __restrict__ adst4,
                            int* __restrict__ alloc, int2* __restrict__ row_desc,
                            int* __restrict__ srclist, float4* __restrict__ sw4) {
    int b = blockIdx.x, t = threadIdx.x, lane = t & 63, wid = t >> 6;
    __shared__ int hist[256], cur[256], ws[4];
    __shared__ int raw[CAPB];       // bucket entries, read once from global
    __shared__ int sorted[5120];    // n + 256 self-loops <= 5056
    __shared__ float4 sadst[256];
    __shared__ int sbase;
    int nid = b * 256 + t;
    hist[t] = (nid < NNODES) ? 1 : 0;          // self-loop counted here
    if (nid < NNODES) sadst[t] = adst4[nid];
    if (b == 0 && t == 0) sw4[ZPAD] = make_float4(0.f, 0.f, 0.f, 0.f);
    __syncthreads();
    int n = bucket_cnt[b * CNTSTRIDE]; if (n > CAPB) n = CAPB;
    for (int i = t; i < n; i += 256) {
        int e = bucketbuf[(size_t)b * CAPB + i];
        raw[i] = e;
        atomicAdd(&hist[e >> 16], 1);
    }
    __syncthreads();
    int v = hist[t];
    int incl = v;
#pragma unroll
    for (int off = 1; off < 64; off <<= 1) {
        int u = __shfl_up(incl, off, 64);
        if (lane >= off) incl += u;
    }
    if (lane == 63) ws[wid] = incl;
    __syncthreads();
    int w0 = ws[0], w1 = ws[1], w2 = ws[2], w3 = ws[3];
    int woff = (wid > 0 ? w0 : 0) + (wid > 1 ? w1 : 0) + (wid > 2 ? w2 : 0);
    int excl = woff + (incl - v);
    int totalb = w0 + w1 + w2 + w3;
    if (t == 0) sbase = atomicAdd(alloc, totalb);    // ONE global atomic per bucket
    __syncthreads();
    int base = sbase;
    cur[t] = excl;
    if (nid < NNODES) row_desc[nid] = make_int2(base + excl, v);
    __syncthreads();
    if (nid < NNODES) {                              // self-loop inserted directly
        int pos = atomicAdd(&cur[t], 1);
        sorted[pos] = (t << 16) | nid;
    }
    for (int i = t; i < n; i += 256) {
        int e = raw[i];
        int pos = atomicAdd(&cur[e >> 16], 1);
        sorted[pos] = e;
    }
    __syncthreads();
    for (int i = t; i < totalb; i += 256) {
        int e = sorted[i];
        int s = e & 0xFFFF, dl = e >> 16;
        srclist[base + i] = s;
        float4 as = asrc4[s];
        float4 ad = sadst[dl];
        float e0 = as.x + ad.x, e1 = as.y + ad.y, e2 = as.z + ad.z, e3 = as.w + ad.w;
        e0 = fmaxf(e0, NEG_SLOPE * e0); e1 = fmaxf(e1, NEG_SLOPE * e1);
        e2 = fmaxf(e2, NEG_SLOPE * e2); e3 = fmaxf(e3, NEG_SLOPE * e3);
        sw4[base + i] = make_float4(__expf(e0), __expf(e1), __expf(e2), __expf(e3));
    }
}

// -------- layer 1 FUSED: aggregate (4 nodes/wave) + W1 proj + ELU + W2 MFMA GEMM ------
__global__ __launch_bounds__(256) void layer1_fused(
        const float* __restrict__ x16, const int2* __restrict__ row_desc,
        const int* __restrict__ srclist, const float4* __restrict__ sw4,
        const float* __restrict__ W1, const float* __restrict__ b1,
        const _Float16* __restrict__ W2T,
        const float* __restrict__ att_src2, const float* __restrict__ att_dst2,
        __half* __restrict__ h2, float* __restrict__ as2, float* __restrict__ ad2) {
    int wid = threadIdx.x >> 6, lane = threadIdx.x & 63;
    int g = lane >> 4, k = lane & 15;
    int base = blockIdx.x * 16 + wid * 4;      // 4 nodes for this wave, 16 per block
    int nid = base + g;
    int2 rd = row_desc[nid];
    int beg = rd.x, cnt = rd.y;
    int cmax = cnt;
    cmax = max(cmax, __shfl_xor(cmax, 16, 64));
    cmax = max(cmax, __shfl_xor(cmax, 32, 64));
    cmax = __builtin_amdgcn_readfirstlane(cmax);
    int gb = g * 16;
    float4 acc = {0.f, 0.f, 0.f, 0.f};
    float4 zs  = {0.f, 0.f, 0.f, 0.f};
    for (int c0 = 0; c0 < cmax; c0 += 16) {
        int sv = (c0 + k < cnt) ? srclist[beg + c0 + k] : 0;   // group's edge buffer
        int bmax = cmax - c0; if (bmax > 16) bmax = 16;
        for (int j = 0; j < bmax; j += 4) {
            int i0 = c0 + j;
            int s0 = __shfl(sv, gb + j + 0, 64);
            int s1 = __shfl(sv, gb + j + 1, 64);
            int s2 = __shfl(sv, gb + j + 2, 64);
            int s3 = __shfl(sv, gb + j + 3, 64);
            int w0i = (i0 + 0 < cnt) ? beg + i0 + 0 : ZPAD;    // index-redirect mask
            int w1i = (i0 + 1 < cnt) ? beg + i0 + 1 : ZPAD;
            int w2i = (i0 + 2 < cnt) ? beg + i0 + 2 : ZPAD;
            int w3i = (i0 + 3 < cnt) ? beg + i0 + 3 : ZPAD;
            float4 w0 = sw4[w0i];
            float4 w1 = sw4[w1i];
            float4 w2 = sw4[w2i];
            float4 w3 = sw4[w3i];
            float x0 = x16[s0 * 16 + k];
            float x1 = x16[s1 * 16 + k];
            float x2 = x16[s2 * 16 + k];
            float x3 = x16[s3 * 16 + k];
            zs.x += (w0.x + w1.x) + (w2.x + w3.x);
            zs.y += (w0.y + w1.y) + (w2.y + w3.y);
            zs.z += (w0.z + w1.z) + (w2.z + w3.z);
            zs.w += (w0.w + w1.w) + (w2.w + w3.w);
            acc.x = fmaf(w3.x, x3, fmaf(w2.x, x2, fmaf(w1.x, x1, fmaf(w0.x, x0, acc.x))));
            acc.y = fmaf(w3.y, x3, fmaf(w2.y, x2, fmaf(w1.y, x1, fmaf(w0.y, x0, acc.y))));
            acc.z = fmaf(w3.z, x3, fmaf(w2.z, x2, fmaf(w1.z, x1, fmaf(w0.z, x0, acc.z))));
            acc.w = fmaf(w3.w, x3, fmaf(w2.w, x2, fmaf(w1.w, x1, fmaf(w0.w, x0, acc.w))));
        }
    }
    __shared__ float sacc[4][4][64];           // [wave][node][h*16+k]
    sacc[wid][g][0 * 16 + k] = acc.x / zs.x;
    sacc[wid][g][1 * 16 + k] = acc.y / zs.y;
    sacc[wid][g][2 * 16 + k] = acc.z / zs.z;
    sacc[wid][g][3 * 16 + k] = acc.w / zs.w;
    // wave-coherent LDS: no barrier. Project 4 nodes with W1 loaded once per kk.
    int c = lane, h2i = c >> 4;
    float4 bo = *(const float4*)(b1 + c * 4);
    float4 o0 = bo, o1 = bo, o2 = bo, o3 = bo;
#pragma unroll
    for (int kk = 0; kk < 15; ++kk) {
        float4 wv = *(const float4*)(W1 + kk * 256 + c * 4);   // L1-resident (15 KB)
        float a0 = sacc[wid][0][h2i * 16 + kk];
        float a1 = sacc[wid][1][h2i * 16 + kk];
        float a2 = sacc[wid][2][h2i * 16 + kk];
        float a3 = sacc[wid][3][h2i * 16 + kk];
        o0.x = fmaf(a0, wv.x, o0.x); o0.y = fmaf(a0, wv.y, o0.y);
        o0.z = fmaf(a0, wv.z, o0.z); o0.w = fmaf(a0, wv.w, o0.w);
        o1.x = fmaf(a1, wv.x, o1.x); o1.y = fmaf(a1, wv.y, o1.y);
        o1.z = fmaf(a1, wv.z, o1.z); o1.w = fmaf(a1, wv.w, o1.w);
        o2.x = fmaf(a2, wv.x, o2.x); o2.y = fmaf(a2, wv.y, o2.y);
        o2.z = fmaf(a2, wv.z, o2.z); o2.w = fmaf(a2, wv.w, o2.w);
        o3.x = fmaf(a3, wv.x, o3.x); o3.y = fmaf(a3, wv.y, o3.y);
        o3.z = fmaf(a3, wv.z, o3.z); o3.w = fmaf(a3, wv.w, o3.w);
    }
    __shared__ _Float16 ot[16][264];           // block's out1 tile (pad 8: 16B-align rows)
    float4 ov[4] = {o0, o1, o2, o3};
#pragma unroll
    for (int gp = 0; gp < 4; ++gp) {
        float p0 = ov[gp].x, p1 = ov[gp].y, p2 = ov[gp].z, p3 = ov[gp].w;
        p0 = p0 > 0.f ? p0 : __expf(p0) - 1.f;   // ELU
        p1 = p1 > 0.f ? p1 : __expf(p1) - 1.f;
        p2 = p2 > 0.f ? p2 : __expf(p2) - 1.f;
        p3 = p3 > 0.f ? p3 : __expf(p3) - 1.f;
        half4 st;
        st[0] = (_Float16)p0; st[1] = (_Float16)p1;
        st[2] = (_Float16)p2; st[3] = (_Float16)p3;
        *(half4*)&ot[wid * 4 + gp][c * 4] = st;
    }
    __syncthreads();
    // ---- phase 2: GEMM 16x256 @ 256x64, wave wid owns N-tile [wid*16, wid*16+16) ----
    int m16 = lane & 15, quad = lane >> 4;
    f32x4 cc = {0.f, 0.f, 0.f, 0.f};
#pragma unroll
    for (int k0 = 0; k0 < 256; k0 += 32) {
        half8 a = *(const half8*)&ot[m16][k0 + quad * 8];
        half8 bf = *(const half8*)(W2T + (size_t)(wid * 16 + m16) * 256 + k0 + quad * 8);
        cc = __builtin_amdgcn_mfma_f32_16x16x32_f16(a, bf, cc, 0, 0, 0);
    }
    __shared__ _Float16 h2t[16][72];
#pragma unroll
    for (int r = 0; r < 4; ++r)
        h2t[quad * 4 + r][wid * 16 + m16] = (_Float16)cc[r];
    __syncthreads();
    int trow = threadIdx.x >> 4, tc = threadIdx.x & 15;   // 16 rows x 16 dim-quads
    int rg = blockIdx.x * 16 + trow;
    half4 hval = *(const half4*)&h2t[trow][tc * 4];
    *(half4*)((_Float16*)h2 + (size_t)rg * 64 + tc * 4) = hval;
    float ps = 0.f, pd = 0.f;
#pragma unroll
    for (int j = 0; j < 4; ++j) {
        float v = (float)hval[j];
        ps += v * att_src2[tc * 4 + j];
        pd += v * att_dst2[tc * 4 + j];
    }
    ps += __shfl_xor(ps, 1, 64); ps += __shfl_xor(ps, 2, 64);
    ps += __shfl_xor(ps, 4, 64); ps += __shfl_xor(ps, 8, 64);
    pd += __shfl_xor(pd, 1, 64); pd += __shfl_xor(pd, 2, 64);
    pd += __shfl_xor(pd, 4, 64); pd += __shfl_xor(pd, 8, 64);
    if (tc == 0) { as2[rg] = ps; ad2[rg] = pd; }
}

// 2 nodes/wave; output accumulated into out_partial[256 slots][64] (no out2 array).
__global__ void layer2_aggr(const __half* __restrict__ h2, const int2* __restrict__ row_desc,
                            const int* __restrict__ srclist,
                            const float* __restrict__ as2, const float* __restrict__ ad2,
                            const float* __restrict__ b2, float* __restrict__ out_partial) {
    int wid = threadIdx.x >> 6, lane = threadIdx.x & 63;
    int sub = lane >> 5, l2 = lane & 31;
    int nid = blockIdx.x * 8 + wid * 2 + sub;
    __shared__ float baccum[64];
    if (threadIdx.x < 64) baccum[threadIdx.x] = 0.f;
    int2 rd = row_desc[nid];
    int beg = rd.x, cnt = rd.y;
    int cmax = max(cnt, __shfl_xor(cnt, 32, 64));
    cmax = __builtin_amdgcn_readfirstlane(cmax);
    float ad = ad2[nid];
    const __half2* hp = (const __half2*)h2;
    __half2 acc2 = __float2half2_rn(0.f);
    float zs = 0.f;
    int sb = sub * 32;
    __syncthreads();
    for (int c0 = 0; c0 < cmax; c0 += 32) {
        int sv = (c0 + l2 < cnt) ? srclist[beg + c0 + l2] : 0;
        int bmax = cmax - c0; if (bmax > 32) bmax = 32;
        for (int j = 0; j < bmax; j += 4) {
#pragma unroll
            for (int u = 0; u < 4; ++u) {
                int jj = j + u;
                int s = __shfl(sv, sb + jj, 64);
                bool valid = (c0 + jj) < cnt;
                float e = as2[s] + ad;
                e = fmaxf(e, NEG_SLOPE * e);
                float wv = valid ? __expf(e) : 0.f;
                __half2 gv = hp[s * 32 + l2];
                zs += wv;
                acc2 = __hfma2(__float2half2_rn(wv), gv, acc2);
            }
        }
    }
    float2 f = __half22float2(acc2);
    float rz = 1.f / zs;
    float2 bo = *(const float2*)(b2 + l2 * 2);
    atomicAdd(&baccum[l2 * 2 + 0], f.x * rz + bo.x);   // LDS: 8 contributions/element
    atomicAdd(&baccum[l2 * 2 + 1], f.y * rz + bo.y);
    __syncthreads();
    if (threadIdx.x < 64)
        atomicAdd(&out_partial[(blockIdx.x & 255) * 64 + threadIdx.x], baccum[threadIdx.x]);
}

// single block: reduce out_partial[256][64] -> dout (direct write, no memset needed)
__global__ void reduce_kernel(const float* __restrict__ out_partial, float* __restrict__ dout) {
    int t = threadIdx.x;
    int col = t & 63, row = t >> 6;
    float acc = 0.f;
    for (int s = row; s < 256; s += 4)
        acc += out_partial[s * 64 + col];
    __shared__ float sh[256];
    sh[t] = acc;
    __syncthreads();
    if (t < 64)
        dout[t] = (sh[t] + sh[t + 64] + sh[t + 128] + sh[t + 192]) * (1.0f / NNODES);
}

// ---------------- launch ----------------

extern "C" void kernel_launch(void* const* d_in, const int* in_sizes, int n_in,
                              void* d_out, int out_size, void* d_ws, size_t ws_size,
                              hipStream_t stream) {
    const float* x        = (const float*)d_in[0];
    const int*   ei       = (const int*)d_in[1];   // [2, E] -> src row then dst row
    const float* W1       = (const float*)d_in[2];
    const float* att_src1 = (const float*)d_in[3];
    const float* att_dst1 = (const float*)d_in[4];
    const float* b1       = (const float*)d_in[5];
    const float* W2       = (const float*)d_in[6];
    const float* att_src2 = (const float*)d_in[7];
    const float* att_dst2 = (const float*)d_in[8];
    const float* b2       = (const float*)d_in[9];
    float* out = (float*)d_out;

    char* ws = (char*)d_ws;
    size_t off = 0;
    auto take = [&](size_t bytes) -> char* {
        char* p = ws + off;
        off = (off + bytes + 255) & ~(size_t)255;
        return p;
    };
    // --- zeroed region: bucket_cnt | alloc | out_partial (contiguous, one memset) ---
    int*      bucket_cnt  = (int*)take((size_t)NB_NODE * CNTSTRIDE * sizeof(int));  // 12544 B
    int*      alloc       = (int*)take(256);                                        // 256 B
    float*    out_partial = (float*)take(256 * 64 * sizeof(float));                 // 65536 B
    size_t    zero_bytes  = (size_t)NB_NODE * CNTSTRIDE * sizeof(int) + 256
                            + 256 * 64 * sizeof(float);
    // --- rest ---
    int*      bucketbuf  = (int*)take((size_t)NB_NODE * CAPB * sizeof(int));
    int2*     row_desc   = (int2*)take((size_t)NNODES * sizeof(int2));
    int*      srclist    = (int*)take(((size_t)NTOT + 64) * sizeof(int));
    float*    sw4        = (float*)take(((size_t)NTOT + 64) * 4 * sizeof(float));
    float*    x16        = (float*)take((size_t)NNODES * 16 * sizeof(float));
    float*    asrc4      = (float*)take((size_t)NNODES * 4 * sizeof(float));
    float*    adst4      = (float*)take((size_t)NNODES * 4 * sizeof(float));
    _Float16* W2T        = (_Float16*)take(64 * 256 * sizeof(_Float16));
    __half*   h2         = (__half*)take((size_t)NNODES * 64 * sizeof(__half));
    float*    as2        = (float*)take((size_t)NNODES * sizeof(float));
    float*    ad2        = (float*)take((size_t)NNODES * sizeof(float));

    const int* srcs = ei;
    const int* dsts = ei + NEDGES;

    hipMemsetAsync(bucket_cnt, 0, zero_bytes, stream);

    setup_scatter<<<NCHUNK + NB_NODE, 256, 0, stream>>>(x, W1, att_src1, att_dst1, W2,
                                                        srcs, dsts, bucket_cnt, bucketbuf,
                                                        x16, asrc4, adst4, W2T);
    sort_kernel<<<NB_NODE, 256, 0, stream>>>(bucket_cnt, bucketbuf,
                                             (const float4*)asrc4, (const float4*)adst4,
                                             alloc, row_desc, srclist, (float4*)sw4);

    layer1_fused<<<NNODES / 16, 256, 0, stream>>>(x16, row_desc, srclist, (const float4*)sw4,
                                                  W1, b1, W2T, att_src2, att_dst2,
                                                  h2, as2, ad2);

    layer2_aggr<<<NNODES / 8, 256, 0, stream>>>(h2, row_desc, srclist, as2, ad2, b2,
                                                out_partial);

    reduce_kernel<<<1, 256, 0, stream>>>(out_partial, out);
}